// Round 1
// baseline (126.067 us; speedup 1.0000x reference)
//
#include <hip/hip_runtime.h>

#define F 128
#define TA 8          // atoms per mlp block
#define NSEG 64
#define CAP 256       // max atoms per segment staged in LDS (seg avg ~96)
#define SPLIT 8       // blocks per segment in pair kernel
#define NPAIRBLK (NSEG * SPLIT)
#define KE 14.3996f

__device__ __forceinline__ float silu_f(float x) {
    return x / (1.0f + expf(-x));
}
__device__ __forceinline__ float softplus_f(float x) {
    return fmaxf(x, 0.0f) + log1pf(expf(-fabsf(x)));
}

// ---------------- Kernel 1: per-atom MLPs (q, c6, rv) + mu projection + seg scan ----------------
// 256 threads. m=tid>>7 picks MLP (0=q, 1=vdw). hq=tid&31 owns hidden units 4hq..4hq+3.
// as=(tid>>5)&3 owns atoms {as, as+4}. No atomics anywhere.
__global__ __launch_bounds__(256) void mlp_kernel(
    const float* __restrict__ h0, const float* __restrict__ h1,
    const int* __restrict__ batch,
    const float* __restrict__ q_w1, const float* __restrict__ q_b1, const float* __restrict__ q_w2,
    const float* __restrict__ vdw_w1, const float* __restrict__ vdw_b1,
    const float* __restrict__ vdw_w2, const float* __restrict__ vdw_b2,
    const float* __restrict__ mu_w,
    float* __restrict__ q_raw, float* __restrict__ c6o, float* __restrict__ rvo,
    float* __restrict__ muo, int* __restrict__ seg_start, int* __restrict__ seg_cnt,
    unsigned* __restrict__ donecnt,
    int N)
{
    __shared__ float h0s[TA][F];          // 4 KB
    const int tid = threadIdx.x;
    const int m  = tid >> 7;              // wave-uniform (waves 0,1 -> q; 2,3 -> vdw)
    const int hq = tid & 31;
    const int as = (tid >> 5) & 3;
    const int base = blockIdx.x * TA;

    // zero the pair-kernel completion counter (workspace is poisoned every iteration)
    if (blockIdx.x == 0 && tid == 64) donecnt[0] = 0u;

    // ---- stage h0 tile: 8 atoms x 128 floats = 256 float4, one per thread ----
    {
        const float4* src = (const float4*)(h0 + (size_t)base * F);
        int a = tid >> 5;
        ((float4*)&h0s[0][0])[tid] =
            (base + a < N) ? src[tid] : make_float4(0.f, 0.f, 0.f, 0.f);
    }
    __syncthreads();

    // ---- layer 1: acc[k][j] = sum_f h0[atom][f] * W1[f][4hq+j], atoms {as, as+4} ----
    const float4* __restrict__ W1v = (const float4*)(m ? vdw_w1 : q_w1);
    float acc[2][4];
    #pragma unroll
    for (int k = 0; k < 2; ++k)
        #pragma unroll
        for (int j = 0; j < 4; ++j) acc[k][j] = 0.0f;

    #pragma unroll 4
    for (int f = 0; f < F; ++f) {
        float4 w = W1v[f * 32 + hq];
        float hv0 = h0s[as][f];
        float hv1 = h0s[as + 4][f];
        acc[0][0] = fmaf(hv0, w.x, acc[0][0]);
        acc[0][1] = fmaf(hv0, w.y, acc[0][1]);
        acc[0][2] = fmaf(hv0, w.z, acc[0][2]);
        acc[0][3] = fmaf(hv0, w.w, acc[0][3]);
        acc[1][0] = fmaf(hv1, w.x, acc[1][0]);
        acc[1][1] = fmaf(hv1, w.y, acc[1][1]);
        acc[1][2] = fmaf(hv1, w.z, acc[1][2]);
        acc[1][3] = fmaf(hv1, w.w, acc[1][3]);
    }

    // ---- activation + layer 2 + 32-lane reduction ----
    if (m == 0) {
        float4 b  = ((const float4*)q_b1)[hq];
        float4 w2 = ((const float4*)q_w2)[hq];
        float part[2];
        #pragma unroll
        for (int k = 0; k < 2; ++k) {
            part[k] = silu_f(acc[k][0] + b.x) * w2.x
                    + silu_f(acc[k][1] + b.y) * w2.y
                    + silu_f(acc[k][2] + b.z) * w2.z
                    + silu_f(acc[k][3] + b.w) * w2.w;
        }
        #pragma unroll
        for (int off = 16; off > 0; off >>= 1)
            #pragma unroll
            for (int k = 0; k < 2; ++k)
                part[k] += __shfl_xor(part[k], off, 64);
        if (hq == 0) {
            #pragma unroll
            for (int k = 0; k < 2; ++k) {
                int n = base + as + 4 * k;
                if (n < N) q_raw[n] = part[k];
            }
        }
    } else {
        float4 b  = ((const float4*)vdw_b1)[hq];
        float4 wA = ((const float4*)vdw_w2)[2 * hq];      // (c6w,rvw) for units 4hq,4hq+1
        float4 wB = ((const float4*)vdw_w2)[2 * hq + 1];  // units 4hq+2,4hq+3
        float pc[2], pr[2];
        #pragma unroll
        for (int k = 0; k < 2; ++k) {
            float s0 = silu_f(acc[k][0] + b.x);
            float s1 = silu_f(acc[k][1] + b.y);
            float s2 = silu_f(acc[k][2] + b.z);
            float s3 = silu_f(acc[k][3] + b.w);
            pc[k] = s0 * wA.x + s1 * wA.z + s2 * wB.x + s3 * wB.z;
            pr[k] = s0 * wA.y + s1 * wA.w + s2 * wB.y + s3 * wB.w;
        }
        #pragma unroll
        for (int off = 16; off > 0; off >>= 1)
            #pragma unroll
            for (int k = 0; k < 2; ++k) {
                pc[k] += __shfl_xor(pc[k], off, 64);
                pr[k] += __shfl_xor(pr[k], off, 64);
            }
        if (hq == 0) {
            float b2c = vdw_b2[0], b2r = vdw_b2[1];
            #pragma unroll
            for (int k = 0; k < 2; ++k) {
                int n = base + as + 4 * k;
                if (n < N) {
                    c6o[n] = softplus_f(pc[k] + b2c);
                    rvo[n] = softplus_f(pr[k] + b2r);
                }
            }
        }
    }

    // ---- mu: wave w handles atoms base+2w, base+2w+1; float2 loads + 6-step shuffle ----
    {
        int lane = tid & 63, wid = tid >> 6;
        float2 wm = ((const float2*)mu_w)[lane];
        #pragma unroll
        for (int r = 0; r < 2; ++r) {
            int n = base + wid * 2 + r;
            if (n < N) {                                  // wave-uniform
                const float2* row = (const float2*)(h1 + (size_t)n * 3 * F);
                float2 v0 = row[lane], v1 = row[64 + lane], v2 = row[128 + lane];
                float p0 = v0.x * wm.x + v0.y * wm.y;
                float p1 = v1.x * wm.x + v1.y * wm.y;
                float p2 = v2.x * wm.x + v2.y * wm.y;
                #pragma unroll
                for (int off = 1; off < 64; off <<= 1) {
                    p0 += __shfl_xor(p0, off, 64);
                    p1 += __shfl_xor(p1, off, 64);
                    p2 += __shfl_xor(p2, off, 64);
                }
                if (lane == 0) {
                    muo[n * 3 + 0] = p0;
                    muo[n * 3 + 1] = p1;
                    muo[n * 3 + 2] = p2;
                }
            }
        }
    }

    // ---- block 0, wave 0: segment starts/counts via binary search (tail work,
    //      overlaps the other 767 blocks; read by pair_kernel after launch boundary) ----
    if (blockIdx.x == 0 && tid < NSEG) {
        int s = tid;
        int lo = 0, hi = N;
        while (lo < hi) { int mid = (lo + hi) >> 1; if (batch[mid] < s) lo = mid + 1; else hi = mid; }
        int lo2 = lo, hi2 = N;
        while (lo2 < hi2) { int mid = (lo2 + hi2) >> 1; if (batch[mid] < s + 1) lo2 = mid + 1; else hi2 = mid; }
        seg_start[s] = lo;
        seg_cnt[s]   = lo2 - lo;
    }
}

// ---------------- Kernel 2: per-segment pairwise energy over UNORDERED pairs (i<j) ----------------
// Every energy term is symmetric under i<->j (n flips sign; both dipole projections flip;
// their product is invariant), so each unordered pair is computed ONCE with weight 1.0
// (reference computes it twice with weight 0.5). Halves the pair-loop VALU work.
template <bool USE_LDS>
__device__ float seg_energy_loop(int start, unsigned ns, unsigned chunk, float mn,
    float inv_s2s, float inv_sig,
    const float* __restrict__ pos, const float* __restrict__ qr,
    const float* __restrict__ c6a, const float* __restrict__ rva,
    const float* __restrict__ mua,
    const float* spos, const float* smu,
    const float* sq, const float* sc, const float* sr)
{
    float e = 0.0f;
    const unsigned total = (ns * (ns - 1u)) >> 1;       // unordered pairs
    const unsigned stride = SPLIT * 256u;
    const float a = (float)(2u * ns - 1u);
    const float a2f = a * a;
    for (unsigned p = chunk * 256u + threadIdx.x; p < total; p += stride) {
        // closed-form triangular decode: largest i with S(i) <= p, S(i) = i*(2ns-i-1)/2
        float disc = a2f - 8.0f * (float)p;             // exact in f32 for ns<=256
        unsigned i = (unsigned)((a - sqrtf(disc)) * 0.5f);
        unsigned Si = (i * (2u * ns - i - 1u)) >> 1;
        while (Si > p) { --i; Si = (i * (2u * ns - i - 1u)) >> 1; }
        while (Si + (ns - 1u - i) <= p) { Si += ns - 1u - i; ++i; }
        unsigned j = p - Si + i + 1u;

        float xi, yi, zi, qi, ci, ri, mxi, myi, mzi;
        float xj, yj, zj, qj, cj, rj, mxj, myj, mzj;
        if constexpr (USE_LDS) {
            xi = spos[3 * i]; yi = spos[3 * i + 1]; zi = spos[3 * i + 2];
            qi = sq[i]; ci = sc[i]; ri = sr[i];
            mxi = smu[3 * i]; myi = smu[3 * i + 1]; mzi = smu[3 * i + 2];
            xj = spos[3 * j]; yj = spos[3 * j + 1]; zj = spos[3 * j + 2];
            qj = sq[j]; cj = sc[j]; rj = sr[j];
            mxj = smu[3 * j]; myj = smu[3 * j + 1]; mzj = smu[3 * j + 2];
        } else {
            int gi = start + (int)i, gj = start + (int)j;
            xi = pos[gi * 3]; yi = pos[gi * 3 + 1]; zi = pos[gi * 3 + 2];
            qi = qr[gi] - mn; ci = c6a[gi]; ri = rva[gi];
            mxi = mua[gi * 3]; myi = mua[gi * 3 + 1]; mzi = mua[gi * 3 + 2];
            xj = pos[gj * 3]; yj = pos[gj * 3 + 1]; zj = pos[gj * 3 + 2];
            qj = qr[gj] - mn; cj = c6a[gj]; rj = rva[gj];
            mxj = mua[gj * 3]; myj = mua[gj * 3 + 1]; mzj = mua[gj * 3 + 2];
        }
        float dx = xi - xj, dy = yi - yj, dz = zi - zj;
        float d2 = dx * dx + dy * dy + dz * dz;
        float dist = sqrtf(d2 + 1e-8f);
        float inv = 1.0f / dist;
        // shielded Coulomb (weight 1.0: unordered pair)
        e += KE * qi * qj * inv * erff(dist * inv_s2s);
        // damped London dispersion: rv_ij^6 == (rv_i*rv_j)^3
        float c6ij = sqrtf(ci * cj);
        float rr = ri * rj;
        float damp = d2 * d2 * d2 + rr * rr * rr;
        e -= c6ij / damp;
        // dipole-dipole
        float nx = dx * inv, ny = dy * inv, nz = dz * inv;
        float mdm = mxi * mxj + myi * myj + mzi * mzj;
        float a1 = mxi * nx + myi * ny + mzi * nz;
        float a2 = mxj * nx + myj * ny + mzj * nz;
        float er = erff(dist * inv_sig);
        float rad = inv * inv * inv * er * er * er;
        e += KE * (mdm - 3.0f * a1 * a2) * rad;
    }
    return e;
}

__global__ __launch_bounds__(256) void pair_kernel(
    const float* __restrict__ pos, const float* __restrict__ qr,
    const float* __restrict__ c6a, const float* __restrict__ rva,
    const float* __restrict__ mua,
    const int* __restrict__ seg_start, const int* __restrict__ seg_cnt,
    const float* __restrict__ sigma_p, float* __restrict__ pairpart,
    unsigned* __restrict__ donecnt, float* __restrict__ out)
{
    __shared__ float spos[3 * CAP], smu[3 * CAP], sq[CAP], sc[CAP], sr[CAP];
    __shared__ float red[4];
    __shared__ float s_mean;
    const int tid = threadIdx.x;
    int s = blockIdx.x & (NSEG - 1);
    unsigned chunk = blockIdx.x >> 6;
    int start = seg_start[s];
    int ns = seg_cnt[s];
    float e = 0.0f;
    if (ns >= 2) {
        float sig = sigma_p[0];
        float inv_s2s = 1.0f / (1.41421356237f * sig);
        float inv_sig = 1.0f / sig;
        bool use_lds = (ns <= CAP);            // block-uniform
        float mn = 0.0f;
        if (use_lds) {
            // coalesced flat staging (pos/mu contiguous per segment)
            for (int jj = tid; jj < 3 * ns; jj += 256) {
                spos[jj] = pos[3 * start + jj];
                smu[jj]  = mua[3 * start + jj];
            }
            for (int jj = tid; jj < ns; jj += 256) {
                sq[jj] = qr[start + jj];
                sc[jj] = c6a[start + jj];
                sr[jj] = rva[start + jj];
            }
            __syncthreads();
            // block-level mean of q
            float ms = 0.0f;
            for (int jj = tid; jj < ns; jj += 256) ms += sq[jj];
            #pragma unroll
            for (int off = 32; off > 0; off >>= 1) ms += __shfl_xor(ms, off, 64);
            if ((tid & 63) == 0) red[tid >> 6] = ms;
            __syncthreads();
            if (tid == 0) s_mean = (red[0] + red[1] + red[2] + red[3]) / (float)ns;
            __syncthreads();
            float m = s_mean;
            for (int jj = tid; jj < ns; jj += 256) sq[jj] -= m;
            __syncthreads();
        } else {
            // global fallback: mean from global reads
            float ms = 0.0f;
            for (int jj = tid; jj < ns; jj += 256) ms += qr[start + jj];
            #pragma unroll
            for (int off = 32; off > 0; off >>= 1) ms += __shfl_xor(ms, off, 64);
            if ((tid & 63) == 0) red[tid >> 6] = ms;
            __syncthreads();
            if (tid == 0) s_mean = (red[0] + red[1] + red[2] + red[3]) / (float)ns;
            __syncthreads();
            mn = s_mean;
        }
        if (use_lds)
            e = seg_energy_loop<true >(start, (unsigned)ns, chunk, mn, inv_s2s, inv_sig,
                                       pos, qr, c6a, rva, mua, spos, smu, sq, sc, sr);
        else
            e = seg_energy_loop<false>(start, (unsigned)ns, chunk, mn, inv_s2s, inv_sig,
                                       pos, qr, c6a, rva, mua, spos, smu, sq, sc, sr);
    }
    // block reduction -> one partial per block (no float atomics; deterministic)
    #pragma unroll
    for (int off = 32; off > 0; off >>= 1) e += __shfl_xor(e, off, 64);
    __shared__ float wsum[4];
    __shared__ unsigned s_rank;
    if ((tid & 63) == 0) wsum[tid >> 6] = e;
    __syncthreads();
    if (tid == 0) {
        pairpart[blockIdx.x] = wsum[0] + wsum[1] + wsum[2] + wsum[3];
        __threadfence();   // release: partial visible before the rank increment
        s_rank = __hip_atomic_fetch_add(donecnt, 1u, __ATOMIC_ACQ_REL,
                                        __HIP_MEMORY_SCOPE_AGENT);
    }
    __syncthreads();
    // last block to finish sums all partials in a FIXED order (deterministic)
    if (s_rank == NPAIRBLK - 1) {
        __threadfence();   // acquire side
        float t = 0.0f;
        for (int i = tid; i < NPAIRBLK; i += 256)
            t += __hip_atomic_load(&pairpart[i], __ATOMIC_RELAXED,
                                   __HIP_MEMORY_SCOPE_AGENT);
        #pragma unroll
        for (int off = 32; off > 0; off >>= 1) t += __shfl_xor(t, off, 64);
        if ((tid & 63) == 0) wsum[tid >> 6] = t;
        __syncthreads();
        if (tid == 0) out[0] = wsum[0] + wsum[1] + wsum[2] + wsum[3];
    }
}

extern "C" void kernel_launch(void* const* d_in, const int* in_sizes, int n_in,
                              void* d_out, int out_size, void* d_ws, size_t ws_size,
                              hipStream_t stream) {
    const float* h0     = (const float*)d_in[0];
    const float* h1     = (const float*)d_in[1];
    const float* pos    = (const float*)d_in[2];
    const int*   batch  = (const int*)d_in[3];
    const float* q_w1   = (const float*)d_in[4];
    const float* q_b1   = (const float*)d_in[5];
    const float* q_w2   = (const float*)d_in[6];
    const float* sigma  = (const float*)d_in[7];
    const float* vdw_w1 = (const float*)d_in[8];
    const float* vdw_b1 = (const float*)d_in[9];
    const float* vdw_w2 = (const float*)d_in[10];
    const float* vdw_b2 = (const float*)d_in[11];
    const float* mu_w   = (const float*)d_in[12];

    int N = in_sizes[0] / F;

    float* ws     = (float*)d_ws;
    float* q_raw  = ws;
    float* c6     = ws + (size_t)N;
    float* rv     = ws + (size_t)2 * N;
    float* mu     = ws + (size_t)3 * N;       // 3N floats
    int*   sstart = (int*)(ws + (size_t)6 * N);  // 64
    int*   scnt   = sstart + NSEG;               // 64
    float* ppart  = (float*)(scnt + NSEG);       // NPAIRBLK
    unsigned* done = (unsigned*)(ppart + NPAIRBLK);

    int blocksA = (N + TA - 1) / TA;
    mlp_kernel<<<blocksA, 256, 0, stream>>>(h0, h1, batch,
        q_w1, q_b1, q_w2, vdw_w1, vdw_b1, vdw_w2, vdw_b2, mu_w,
        q_raw, c6, rv, mu, sstart, scnt, done, N);

    pair_kernel<<<NPAIRBLK, 256, 0, stream>>>(pos, q_raw, c6, rv, mu,
        sstart, scnt, sigma, ppart, done, (float*)d_out);
}

// Round 2
// 109.822 us; speedup vs baseline: 1.1479x; 1.1479x over previous
//
#include <hip/hip_runtime.h>

#define F 128
#define TA 8          // atoms per mlp block
#define NSEG 64
#define CAP 256       // max atoms per segment staged in LDS (seg avg ~96)
#define SPLIT 8       // blocks per segment in pair kernel
#define NPAIRBLK (NSEG * SPLIT)
#define KE 14.3996f

__device__ __forceinline__ float silu_f(float x) {
    return x / (1.0f + expf(-x));
}
__device__ __forceinline__ float softplus_f(float x) {
    return fmaxf(x, 0.0f) + log1pf(expf(-fabsf(x)));
}

// ---------------- Kernel 1: per-atom MLPs (q, c6, rv) + mu projection + seg scan ----------------
// 256 threads. m=tid>>7 picks MLP (0=q, 1=vdw). hq=tid&31 owns hidden units 4hq..4hq+3.
// as=(tid>>5)&3 owns atoms {as, as+4}. No atomics anywhere.
__global__ __launch_bounds__(256) void mlp_kernel(
    const float* __restrict__ h0, const float* __restrict__ h1,
    const int* __restrict__ batch,
    const float* __restrict__ q_w1, const float* __restrict__ q_b1, const float* __restrict__ q_w2,
    const float* __restrict__ vdw_w1, const float* __restrict__ vdw_b1,
    const float* __restrict__ vdw_w2, const float* __restrict__ vdw_b2,
    const float* __restrict__ mu_w,
    float* __restrict__ q_raw, float* __restrict__ c6o, float* __restrict__ rvo,
    float* __restrict__ muo, int* __restrict__ seg_start, int* __restrict__ seg_cnt,
    int N)
{
    __shared__ float h0s[TA][F];          // 4 KB
    const int tid = threadIdx.x;
    const int m  = tid >> 7;              // wave-uniform (waves 0,1 -> q; 2,3 -> vdw)
    const int hq = tid & 31;
    const int as = (tid >> 5) & 3;
    const int base = blockIdx.x * TA;

    // ---- stage h0 tile: 8 atoms x 128 floats = 256 float4, one per thread ----
    {
        const float4* src = (const float4*)(h0 + (size_t)base * F);
        int a = tid >> 5;
        ((float4*)&h0s[0][0])[tid] =
            (base + a < N) ? src[tid] : make_float4(0.f, 0.f, 0.f, 0.f);
    }
    __syncthreads();

    // ---- layer 1: acc[k][j] = sum_f h0[atom][f] * W1[f][4hq+j], atoms {as, as+4} ----
    const float4* __restrict__ W1v = (const float4*)(m ? vdw_w1 : q_w1);
    float acc[2][4];
    #pragma unroll
    for (int k = 0; k < 2; ++k)
        #pragma unroll
        for (int j = 0; j < 4; ++j) acc[k][j] = 0.0f;

    #pragma unroll 4
    for (int f = 0; f < F; ++f) {
        float4 w = W1v[f * 32 + hq];
        float hv0 = h0s[as][f];
        float hv1 = h0s[as + 4][f];
        acc[0][0] = fmaf(hv0, w.x, acc[0][0]);
        acc[0][1] = fmaf(hv0, w.y, acc[0][1]);
        acc[0][2] = fmaf(hv0, w.z, acc[0][2]);
        acc[0][3] = fmaf(hv0, w.w, acc[0][3]);
        acc[1][0] = fmaf(hv1, w.x, acc[1][0]);
        acc[1][1] = fmaf(hv1, w.y, acc[1][1]);
        acc[1][2] = fmaf(hv1, w.z, acc[1][2]);
        acc[1][3] = fmaf(hv1, w.w, acc[1][3]);
    }

    // ---- activation + layer 2 + 32-lane reduction ----
    if (m == 0) {
        float4 b  = ((const float4*)q_b1)[hq];
        float4 w2 = ((const float4*)q_w2)[hq];
        float part[2];
        #pragma unroll
        for (int k = 0; k < 2; ++k) {
            part[k] = silu_f(acc[k][0] + b.x) * w2.x
                    + silu_f(acc[k][1] + b.y) * w2.y
                    + silu_f(acc[k][2] + b.z) * w2.z
                    + silu_f(acc[k][3] + b.w) * w2.w;
        }
        #pragma unroll
        for (int off = 16; off > 0; off >>= 1)
            #pragma unroll
            for (int k = 0; k < 2; ++k)
                part[k] += __shfl_xor(part[k], off, 64);
        if (hq == 0) {
            #pragma unroll
            for (int k = 0; k < 2; ++k) {
                int n = base + as + 4 * k;
                if (n < N) q_raw[n] = part[k];
            }
        }
    } else {
        float4 b  = ((const float4*)vdw_b1)[hq];
        float4 wA = ((const float4*)vdw_w2)[2 * hq];      // (c6w,rvw) for units 4hq,4hq+1
        float4 wB = ((const float4*)vdw_w2)[2 * hq + 1];  // units 4hq+2,4hq+3
        float pc[2], pr[2];
        #pragma unroll
        for (int k = 0; k < 2; ++k) {
            float s0 = silu_f(acc[k][0] + b.x);
            float s1 = silu_f(acc[k][1] + b.y);
            float s2 = silu_f(acc[k][2] + b.z);
            float s3 = silu_f(acc[k][3] + b.w);
            pc[k] = s0 * wA.x + s1 * wA.z + s2 * wB.x + s3 * wB.z;
            pr[k] = s0 * wA.y + s1 * wA.w + s2 * wB.y + s3 * wB.w;
        }
        #pragma unroll
        for (int off = 16; off > 0; off >>= 1)
            #pragma unroll
            for (int k = 0; k < 2; ++k) {
                pc[k] += __shfl_xor(pc[k], off, 64);
                pr[k] += __shfl_xor(pr[k], off, 64);
            }
        if (hq == 0) {
            float b2c = vdw_b2[0], b2r = vdw_b2[1];
            #pragma unroll
            for (int k = 0; k < 2; ++k) {
                int n = base + as + 4 * k;
                if (n < N) {
                    c6o[n] = softplus_f(pc[k] + b2c);
                    rvo[n] = softplus_f(pr[k] + b2r);
                }
            }
        }
    }

    // ---- mu: wave w handles atoms base+2w, base+2w+1; float2 loads + 6-step shuffle ----
    {
        int lane = tid & 63, wid = tid >> 6;
        float2 wm = ((const float2*)mu_w)[lane];
        #pragma unroll
        for (int r = 0; r < 2; ++r) {
            int n = base + wid * 2 + r;
            if (n < N) {                                  // wave-uniform
                const float2* row = (const float2*)(h1 + (size_t)n * 3 * F);
                float2 v0 = row[lane], v1 = row[64 + lane], v2 = row[128 + lane];
                float p0 = v0.x * wm.x + v0.y * wm.y;
                float p1 = v1.x * wm.x + v1.y * wm.y;
                float p2 = v2.x * wm.x + v2.y * wm.y;
                #pragma unroll
                for (int off = 1; off < 64; off <<= 1) {
                    p0 += __shfl_xor(p0, off, 64);
                    p1 += __shfl_xor(p1, off, 64);
                    p2 += __shfl_xor(p2, off, 64);
                }
                if (lane == 0) {
                    muo[n * 3 + 0] = p0;
                    muo[n * 3 + 1] = p1;
                    muo[n * 3 + 2] = p2;
                }
            }
        }
    }

    // ---- block 0, wave 0: segment starts/counts via binary search (tail work,
    //      overlaps the other 767 blocks; read by pair_kernel after launch boundary) ----
    if (blockIdx.x == 0 && tid < NSEG) {
        int s = tid;
        int lo = 0, hi = N;
        while (lo < hi) { int mid = (lo + hi) >> 1; if (batch[mid] < s) lo = mid + 1; else hi = mid; }
        int lo2 = lo, hi2 = N;
        while (lo2 < hi2) { int mid = (lo2 + hi2) >> 1; if (batch[mid] < s + 1) lo2 = mid + 1; else hi2 = mid; }
        seg_start[s] = lo;
        seg_cnt[s]   = lo2 - lo;
    }
}

// ---------------- Kernel 2: per-segment pairwise energy over UNORDERED pairs (i<j) ----------------
// Every energy term is symmetric under i<->j (n flips sign; both dipole projections flip;
// their product is invariant), so each unordered pair is computed ONCE with weight 1.0
// (reference computes it twice with weight 0.5). Staged values are pre-transformed:
//   sq = q - mean(q),  sc = sqrt(c6)  (so c6_ij = sc_i*sc_j),
//   sr = rv^3          (so rv_ij^6 = (rv_i*rv_j)^3 = sr_i*sr_j).
template <bool USE_LDS>
__device__ float seg_energy_loop(int start, unsigned ns, unsigned chunk, float mn,
    float inv_s2s, float inv_sig,
    const float* __restrict__ pos, const float* __restrict__ qr,
    const float* __restrict__ c6a, const float* __restrict__ rva,
    const float* __restrict__ mua,
    const float* spos, const float* smu,
    const float* sq, const float* sc, const float* sr)
{
    float e_ke   = 0.0f;   // Coulomb + dipole (share the KE prefactor)
    float e_disp = 0.0f;   // dispersion (no prefactor)
    const unsigned total = (ns * (ns - 1u)) >> 1;       // unordered pairs
    const unsigned stride = SPLIT * 256u;
    const float a = (float)(2u * ns - 1u);
    const float a2f = a * a;
    for (unsigned p = chunk * 256u + threadIdx.x; p < total; p += stride) {
        // closed-form triangular decode: largest i with S(i) <= p, S(i) = i*(2ns-i-1)/2
        float disc = a2f - 8.0f * (float)p;             // exact in f32 for ns<=256
        unsigned i = (unsigned)((a - sqrtf(disc)) * 0.5f);
        unsigned Si = (i * (2u * ns - i - 1u)) >> 1;
        while (Si > p) { --i; Si = (i * (2u * ns - i - 1u)) >> 1; }
        while (Si + (ns - 1u - i) <= p) { Si += ns - 1u - i; ++i; }
        unsigned j = p - Si + i + 1u;

        float xi, yi, zi, qi, ci, ri, mxi, myi, mzi;
        float xj, yj, zj, qj, cj, rj, mxj, myj, mzj;
        if constexpr (USE_LDS) {
            xi = spos[3 * i]; yi = spos[3 * i + 1]; zi = spos[3 * i + 2];
            qi = sq[i]; ci = sc[i]; ri = sr[i];
            mxi = smu[3 * i]; myi = smu[3 * i + 1]; mzi = smu[3 * i + 2];
            xj = spos[3 * j]; yj = spos[3 * j + 1]; zj = spos[3 * j + 2];
            qj = sq[j]; cj = sc[j]; rj = sr[j];
            mxj = smu[3 * j]; myj = smu[3 * j + 1]; mzj = smu[3 * j + 2];
        } else {
            int gi = start + (int)i, gj = start + (int)j;
            xi = pos[gi * 3]; yi = pos[gi * 3 + 1]; zi = pos[gi * 3 + 2];
            qi = qr[gi] - mn; ci = sqrtf(c6a[gi]);
            { float r = rva[gi]; ri = r * r * r; }
            mxi = mua[gi * 3]; myi = mua[gi * 3 + 1]; mzi = mua[gi * 3 + 2];
            xj = pos[gj * 3]; yj = pos[gj * 3 + 1]; zj = pos[gj * 3 + 2];
            qj = qr[gj] - mn; cj = sqrtf(c6a[gj]);
            { float r = rva[gj]; rj = r * r * r; }
            mxj = mua[gj * 3]; myj = mua[gj * 3 + 1]; mzj = mua[gj * 3 + 2];
        }
        float dx = xi - xj, dy = yi - yj, dz = zi - zj;
        float d2 = dx * dx + dy * dy + dz * dz;
        float dist = sqrtf(d2 + 1e-8f);
        float inv = 1.0f / dist;
        // shielded Coulomb (weight 1.0: unordered pair; KE applied once at the end)
        e_ke += qi * qj * inv * erff(dist * inv_s2s);
        // damped London dispersion: c6_ij = ci*cj, rv_ij^6 = ri*rj (staged cubes)
        float damp = d2 * d2 * d2 + ri * rj;
        e_disp += (ci * cj) / damp;
        // dipole-dipole
        float nx = dx * inv, ny = dy * inv, nz = dz * inv;
        float mdm = mxi * mxj + myi * myj + mzi * mzj;
        float a1 = mxi * nx + myi * ny + mzi * nz;
        float a2 = mxj * nx + myj * ny + mzj * nz;
        float er = erff(dist * inv_sig);
        float rad = inv * inv * inv * er * er * er;
        e_ke += (mdm - 3.0f * a1 * a2) * rad;
    }
    return KE * e_ke - e_disp;
}

__global__ __launch_bounds__(256) void pair_kernel(
    const float* __restrict__ pos, const float* __restrict__ qr,
    const float* __restrict__ c6a, const float* __restrict__ rva,
    const float* __restrict__ mua,
    const int* __restrict__ seg_start, const int* __restrict__ seg_cnt,
    const float* __restrict__ sigma_p, float* __restrict__ pairpart)
{
    __shared__ float spos[3 * CAP], smu[3 * CAP], sq[CAP], sc[CAP], sr[CAP];
    __shared__ float red[4];
    __shared__ float s_mean;
    const int tid = threadIdx.x;
    int s = blockIdx.x & (NSEG - 1);
    unsigned chunk = blockIdx.x >> 6;
    int start = seg_start[s];
    int ns = seg_cnt[s];
    float e = 0.0f;
    if (ns >= 2) {
        float sig = sigma_p[0];
        float inv_s2s = 1.0f / (1.41421356237f * sig);
        float inv_sig = 1.0f / sig;
        bool use_lds = (ns <= CAP);            // block-uniform
        float mn = 0.0f;
        if (use_lds) {
            // coalesced flat staging (pos/mu contiguous per segment)
            for (int jj = tid; jj < 3 * ns; jj += 256) {
                spos[jj] = pos[3 * start + jj];
                smu[jj]  = mua[3 * start + jj];
            }
            for (int jj = tid; jj < ns; jj += 256) {
                sq[jj] = qr[start + jj];
                sc[jj] = sqrtf(c6a[start + jj]);   // pre-sqrt: c6_ij = sc_i*sc_j
                float r = rva[start + jj];
                sr[jj] = r * r * r;                // pre-cube: rv_ij^6 = sr_i*sr_j
            }
            __syncthreads();
            // block-level mean of q
            float ms = 0.0f;
            for (int jj = tid; jj < ns; jj += 256) ms += sq[jj];
            #pragma unroll
            for (int off = 32; off > 0; off >>= 1) ms += __shfl_xor(ms, off, 64);
            if ((tid & 63) == 0) red[tid >> 6] = ms;
            __syncthreads();
            if (tid == 0) s_mean = (red[0] + red[1] + red[2] + red[3]) / (float)ns;
            __syncthreads();
            float m = s_mean;
            for (int jj = tid; jj < ns; jj += 256) sq[jj] -= m;
            __syncthreads();
        } else {
            // global fallback: mean from global reads
            float ms = 0.0f;
            for (int jj = tid; jj < ns; jj += 256) ms += qr[start + jj];
            #pragma unroll
            for (int off = 32; off > 0; off >>= 1) ms += __shfl_xor(ms, off, 64);
            if ((tid & 63) == 0) red[tid >> 6] = ms;
            __syncthreads();
            if (tid == 0) s_mean = (red[0] + red[1] + red[2] + red[3]) / (float)ns;
            __syncthreads();
            mn = s_mean;
        }
        if (use_lds)
            e = seg_energy_loop<true >(start, (unsigned)ns, chunk, mn, inv_s2s, inv_sig,
                                       pos, qr, c6a, rva, mua, spos, smu, sq, sc, sr);
        else
            e = seg_energy_loop<false>(start, (unsigned)ns, chunk, mn, inv_s2s, inv_sig,
                                       pos, qr, c6a, rva, mua, spos, smu, sq, sc, sr);
    }
    // block reduction -> one partial per block (no global atomics)
    #pragma unroll
    for (int off = 32; off > 0; off >>= 1) e += __shfl_xor(e, off, 64);
    __shared__ float wsum[4];
    if ((tid & 63) == 0) wsum[tid >> 6] = e;
    __syncthreads();
    if (tid == 0) pairpart[blockIdx.x] = wsum[0] + wsum[1] + wsum[2] + wsum[3];
}

// ---------------- Kernel 3: final reduction of block partials ----------------
__global__ __launch_bounds__(256) void final_kernel(
    const float* __restrict__ pairpart, float* __restrict__ out, int n)
{
    float e = 0.0f;
    for (int i = threadIdx.x; i < n; i += 256) e += pairpart[i];
    #pragma unroll
    for (int off = 32; off > 0; off >>= 1) e += __shfl_xor(e, off, 64);
    __shared__ float wsum[4];
    if ((threadIdx.x & 63) == 0) wsum[threadIdx.x >> 6] = e;
    __syncthreads();
    if (threadIdx.x == 0) out[0] = wsum[0] + wsum[1] + wsum[2] + wsum[3];
}

extern "C" void kernel_launch(void* const* d_in, const int* in_sizes, int n_in,
                              void* d_out, int out_size, void* d_ws, size_t ws_size,
                              hipStream_t stream) {
    const float* h0     = (const float*)d_in[0];
    const float* h1     = (const float*)d_in[1];
    const float* pos    = (const float*)d_in[2];
    const int*   batch  = (const int*)d_in[3];
    const float* q_w1   = (const float*)d_in[4];
    const float* q_b1   = (const float*)d_in[5];
    const float* q_w2   = (const float*)d_in[6];
    const float* sigma  = (const float*)d_in[7];
    const float* vdw_w1 = (const float*)d_in[8];
    const float* vdw_b1 = (const float*)d_in[9];
    const float* vdw_w2 = (const float*)d_in[10];
    const float* vdw_b2 = (const float*)d_in[11];
    const float* mu_w   = (const float*)d_in[12];

    int N = in_sizes[0] / F;

    float* ws     = (float*)d_ws;
    float* q_raw  = ws;
    float* c6     = ws + (size_t)N;
    float* rv     = ws + (size_t)2 * N;
    float* mu     = ws + (size_t)3 * N;       // 3N floats
    int*   sstart = (int*)(ws + (size_t)6 * N);  // 64
    int*   scnt   = sstart + NSEG;               // 64
    float* ppart  = (float*)(scnt + NSEG);       // NPAIRBLK

    int blocksA = (N + TA - 1) / TA;
    mlp_kernel<<<blocksA, 256, 0, stream>>>(h0, h1, batch,
        q_w1, q_b1, q_w2, vdw_w1, vdw_b1, vdw_w2, vdw_b2, mu_w,
        q_raw, c6, rv, mu, sstart, scnt, N);

    pair_kernel<<<NPAIRBLK, 256, 0, stream>>>(pos, q_raw, c6, rv, mu,
        sstart, scnt, sigma, ppart);

    final_kernel<<<1, 256, 0, stream>>>(ppart, (float*)d_out, NPAIRBLK);
}